// Round 3
// baseline (586.793 us; speedup 1.0000x reference)
//
#include <hip/hip_runtime.h>

typedef unsigned short u16;
typedef unsigned short u16x4 __attribute__((ext_vector_type(4)));
typedef unsigned short u16x8 __attribute__((ext_vector_type(8)));
typedef short bf16x8 __attribute__((ext_vector_type(8)));
typedef float f32x4 __attribute__((ext_vector_type(4)));

#define EPSF 1e-5f

// Geometry
#define NB   64
#define C1   512
#define C2   128
#define C3   32
#define HH   28
#define WW   28
#define HW   784            // 28*28
#define NHW  50176          // 64*784
#define XELEMS 25690112     // 64*512*784

// ws layout (bytes); total ~= 12.45 MiB
#define WS_SC     0         // 4 x u32: mn1,mx1,mn2,mx2 (bit-punned non-neg floats)
#define WS_BN1I   64        // 512 f32
#define WS_BN1B   2112      // 512 f32
#define WS_BN2I   4160      // 128 f32
#define WS_BN2B   4672      // 128 f32
#define WS_WQ1    5376      // 128*512 bf16
#define WS_WQ2    136448    // 9*32*128 bf16, packed [tap][co][ci]
#define WS_H2     210176    // 50176*128 bf16 (NHWC)

__device__ __forceinline__ float bf2f(u16 u) { return __uint_as_float(((unsigned)u) << 16); }
__device__ __forceinline__ u16 f2bf(float f) {
  unsigned x = __float_as_uint(f);
  return (u16)((x + 0x7fffu + ((x >> 16) & 1u)) >> 16);
}
// bit-level non-finite -> 0 (immune to fast-math); no-op for clean data
__device__ __forceinline__ float finz(float f) {
  unsigned u = __float_as_uint(f);
  return ((u & 0x7f800000u) == 0x7f800000u) ? 0.0f : f;
}

// ---------------------------------------------------------------------------
// K_w: weight quantization + BN tables + scalar init.  2 blocks x 256.
// ---------------------------------------------------------------------------
__global__ void kw_kernel(const float* g1, const float* be1, const float* m1, const float* v1,
                          const float* w1,
                          const float* g2, const float* be2, const float* m2, const float* v2,
                          const float* w2, unsigned char* ws) {
  float* bn1i = (float*)(ws + WS_BN1I);
  float* bn1b = (float*)(ws + WS_BN1B);
  float* bn2i = (float*)(ws + WS_BN2I);
  float* bn2b = (float*)(ws + WS_BN2B);
  u16* wq1 = (u16*)(ws + WS_WQ1);
  u16* wq2 = (u16*)(ws + WS_WQ2);
  unsigned* sc = (unsigned*)(ws + WS_SC);
  __shared__ float red[512];
  const int t = threadIdx.x;

  if (blockIdx.x == 0) {
    if (t == 0) { sc[0] = 0x7f7fffffu; sc[1] = 0u; sc[2] = 0x7f7fffffu; sc[3] = 0u; }
    for (int c = t; c < C1; c += 256) {
      float inv = g1[c] / sqrtf(v1[c] + EPSF);
      bn1i[c] = inv;
      bn1b[c] = be1[c] - m1[c] * inv;
    }
    if (t < C2) {
      float inv = g2[t] / sqrtf(v2[t] + EPSF);
      bn2i[t] = inv;
      bn2b[t] = be2[t] - m2[t] * inv;
    }
    // w1 min/max (values can be negative -> in-block LDS reduce, no atomics)
    float mn = 3.4e38f, mx = -3.4e38f;
    for (int i = t; i < C2 * C1; i += 256) {
      float f = finz(w1[i]); mn = fminf(mn, f); mx = fmaxf(mx, f);
    }
    red[t] = mn; red[256 + t] = mx;
    __syncthreads();
    for (int s = 128; s > 0; s >>= 1) {
      if (t < s) { red[t] = fminf(red[t], red[t + s]); red[256 + t] = fmaxf(red[256 + t], red[256 + t + s]); }
      __syncthreads();
    }
    mn = red[0]; mx = red[256];
    float scale = fmaxf((mx - mn) / 255.0f, 1e-8f);
    float rs = 1.0f / scale;
    for (int i = t; i < C2 * C1; i += 256) {
      float f = finz(w1[i]);
      wq1[i] = f2bf(fmaf(rintf((f - mn) * rs), scale, mn));
    }
  } else {
    float mn = 3.4e38f, mx = -3.4e38f;
    for (int i = t; i < C3 * C2 * 9; i += 256) {
      float f = finz(w2[i]); mn = fminf(mn, f); mx = fmaxf(mx, f);
    }
    red[t] = mn; red[256 + t] = mx;
    __syncthreads();
    for (int s = 128; s > 0; s >>= 1) {
      if (t < s) { red[t] = fminf(red[t], red[t + s]); red[256 + t] = fmaxf(red[256 + t], red[256 + t + s]); }
      __syncthreads();
    }
    mn = red[0]; mx = red[256];
    float scale = fmaxf((mx - mn) / 255.0f, 1e-8f);
    float rs = 1.0f / scale;
    // pack: wq2[tap*4096 + co*128 + ci] = q(w2[(co*128+ci)*9 + tap])
    for (int o = t; o < C3 * C2 * 9; o += 256) {
      int tap = o >> 12;            // 0..8
      int rem = o & 4095;           // co*128 + ci
      float f = finz(w2[rem * 9 + tap]);
      wq2[o] = f2bf(fmaf(rintf((f - mn) * rs), scale, mn));
    }
  }
}

// ---------------------------------------------------------------------------
// K1: global min/max of relu(bn1(x)).  Values >= 0 -> uint-punned atomics.
// ---------------------------------------------------------------------------
__global__ void k1_minmax(const float* __restrict__ x, unsigned char* ws) {
  const float* bn1i = (const float*)(ws + WS_BN1I);
  const float* bn1b = (const float*)(ws + WS_BN1B);
  unsigned* sc = (unsigned*)(ws + WS_SC);
  int gid = blockIdx.x * blockDim.x + threadIdx.x;
  int stride = gridDim.x * blockDim.x;
  const int ngroups = XELEMS / 4;
  float mn = 3.4e38f, mx = 0.0f;
  for (int i = gid; i < ngroups; i += stride) {
    int base = i * 4;
    int c = (base / HW) & (C1 - 1);        // 784 % 4 == 0 so group is single-channel
    float inv = bn1i[c], bb = bn1b[c];
    f32x4 u = *((const f32x4*)x + i);
#pragma unroll
    for (int j = 0; j < 4; j++) {
      float f = finz(fmaxf(fmaf(u[j], inv, bb), 0.0f));
      mn = fminf(mn, f); mx = fmaxf(mx, f);
    }
  }
  for (int m = 32; m; m >>= 1) {
    mn = fminf(mn, __shfl_xor(mn, m));
    mx = fmaxf(mx, __shfl_xor(mx, m));
  }
  if ((threadIdx.x & 63) == 0) {
    atomicMin(&sc[0], __float_as_uint(mn));
    atomicMax(&sc[1], __float_as_uint(mx));
  }
}

// ---------------------------------------------------------------------------
// conv1: 1x1 conv as MFMA GEMM.  C[co=128][sp] = wq1[128x512] * xq[512][sp].
// Block = 256 thr (4 waves, 2x2), tile 128co x 128sp, BK=32, K=512.
// x staged with fused bn1+relu+quant and write-side transpose into LDS [sp][k].
// Epilogue: bn2+relu -> h2 (NHWC bf16) + global min/max atomics.
// ---------------------------------------------------------------------------
__global__ __launch_bounds__(256) void conv1_kernel(const float* __restrict__ x,
                                                    unsigned char* ws) {
  const float* bn1i = (const float*)(ws + WS_BN1I);
  const float* bn1b = (const float*)(ws + WS_BN1B);
  const float* bn2i = (const float*)(ws + WS_BN2I);
  const float* bn2b = (const float*)(ws + WS_BN2B);
  const u16* wq1 = (const u16*)(ws + WS_WQ1);
  u16* h2 = (u16*)(ws + WS_H2);
  unsigned* sc = (unsigned*)(ws + WS_SC);

  __shared__ __align__(16) u16 Alds[128 * 40];   // [co][k], pad row to 40
  __shared__ __align__(16) u16 Blds[128 * 40];   // [sp][k] transposed, pad 40

  const int t = threadIdx.x;
  const int sp0 = blockIdx.x * 128;

  const float mn1 = finz(__uint_as_float(sc[0]));
  const float mx1 = finz(__uint_as_float(sc[1]));
  const float s1 = fmaxf((mx1 - mn1) / 255.0f, 1e-8f);
  const float r1 = 1.0f / s1;

  // x staging assignment: thread -> k-row kk (0..31), sp groups of 8
  const int kk = t >> 3;
  const int spA = (t & 7) * 8;
  const int spB = 64 + spA;
  const int ga = sp0 + spA, gb = sp0 + spB;
  const int na = ga / HW, hwa = ga % HW;
  const int nb = gb / HW, hwb = gb % HW;
  const float* xA = x + na * (C1 * HW) + hwa;
  const float* xB = x + nb * (C1 * HW) + hwb;

  // wq1 staging: thread -> co = t>>1, k offset (t&1)*16
  const int wco = t >> 1;
  const int wko = (t & 1) * 16;

  const int lane = t & 63;
  const int l15 = lane & 15;
  const int q = lane >> 4;
  const int wv = t >> 6;
  const int wy = wv >> 1;   // co half (0/1)
  const int wx = wv & 1;    // sp half (0/1)

  f32x4 acc[4][4] = {};

  for (int k0 = 0; k0 < C1; k0 += 32) {
    __syncthreads();
    {  // stage wq1 slice [128co x 32k]
      const u16* src = wq1 + wco * C1 + k0 + wko;
      u16x8 a0 = *(const u16x8*)(src);
      u16x8 a1 = *(const u16x8*)(src + 8);
      *(u16x8*)&Alds[wco * 40 + wko] = a0;
      *(u16x8*)&Alds[wco * 40 + wko + 8] = a1;
    }
    {  // stage x slice [32k x 128sp] with bn1+relu+quant, transpose into [sp][k]
      int c = k0 + kk;
      float inv = bn1i[c], bb = bn1b[c];
      f32x4 va0 = *(const f32x4*)(xA + c * HW);
      f32x4 va1 = *(const f32x4*)(xA + c * HW + 4);
      f32x4 vb0 = *(const f32x4*)(xB + c * HW);
      f32x4 vb1 = *(const f32x4*)(xB + c * HW + 4);
#pragma unroll
      for (int j = 0; j < 4; j++) {
        float f0 = finz(fmaxf(fmaf(va0[j], inv, bb), 0.0f));
        Blds[(spA + j) * 40 + kk] = f2bf(fmaf(rintf((f0 - mn1) * r1), s1, mn1));
        float f1 = finz(fmaxf(fmaf(va1[j], inv, bb), 0.0f));
        Blds[(spA + 4 + j) * 40 + kk] = f2bf(fmaf(rintf((f1 - mn1) * r1), s1, mn1));
        float g0 = finz(fmaxf(fmaf(vb0[j], inv, bb), 0.0f));
        Blds[(spB + j) * 40 + kk] = f2bf(fmaf(rintf((g0 - mn1) * r1), s1, mn1));
        float g1v = finz(fmaxf(fmaf(vb1[j], inv, bb), 0.0f));
        Blds[(spB + 4 + j) * 40 + kk] = f2bf(fmaf(rintf((g1v - mn1) * r1), s1, mn1));
      }
    }
    __syncthreads();
    bf16x8 af[4], bfr[4];
#pragma unroll
    for (int i = 0; i < 4; i++) {
      af[i] = *(const bf16x8*)&Alds[(wy * 64 + i * 16 + l15) * 40 + q * 8];
      bfr[i] = *(const bf16x8*)&Blds[(wx * 64 + i * 16 + l15) * 40 + q * 8];
    }
#pragma unroll
    for (int i = 0; i < 4; i++)
#pragma unroll
      for (int j = 0; j < 4; j++)
        acc[i][j] = __builtin_amdgcn_mfma_f32_16x16x32_bf16(af[i], bfr[j], acc[i][j], 0, 0, 0);
  }

  // epilogue: bn2 + relu, store h2 NHWC bf16, track min/max (on fp32 values)
  float lmn = 3.4e38f, lmx = 0.0f;
#pragma unroll
  for (int i = 0; i < 4; i++) {
    int cob = wy * 64 + i * 16 + q * 4;           // D row = q*4 + reg
    f32x4 i2 = *(const f32x4*)&bn2i[cob];
    f32x4 b2 = *(const f32x4*)&bn2b[cob];
#pragma unroll
    for (int j = 0; j < 4; j++) {
      int sp = sp0 + wx * 64 + j * 16 + l15;      // D col = lane&15
      u16x4 v;
#pragma unroll
      for (int r = 0; r < 4; r++) {
        float h = finz(fmaxf(fmaf(acc[i][j][r], i2[r], b2[r]), 0.0f));
        v[r] = f2bf(h);
        lmn = fminf(lmn, h); lmx = fmaxf(lmx, h);
      }
      *(u16x4*)&h2[sp * C2 + cob] = v;
    }
  }
  for (int m = 32; m; m >>= 1) {
    lmn = fminf(lmn, __shfl_xor(lmn, m));
    lmx = fmaxf(lmx, __shfl_xor(lmx, m));
  }
  if (l15 == 0 && q == 0) {
    atomicMin(&sc[2], __float_as_uint(lmn));
    atomicMax(&sc[3], __float_as_uint(lmx));
  }
}

// ---------------------------------------------------------------------------
// conv2: 3x3 conv (pad 1) as direct MFMA.  A = wq2pack[tap][co][ci] (global),
// B = h2 NHWC bf16 with on-the-fly quant + boundary masking.  Wave = 32co x 32sp.
// Output fp32 NCHW.
// ---------------------------------------------------------------------------
__global__ __launch_bounds__(256) void conv2_kernel(const unsigned char* ws,
                                                    float* __restrict__ out) {
  const u16* wq2 = (const u16*)(ws + WS_WQ2);
  const u16* h2 = (const u16*)(ws + WS_H2);
  const unsigned* sc = (const unsigned*)(ws + WS_SC);
  const float mn2 = finz(__uint_as_float(sc[2]));
  const float mx2 = finz(__uint_as_float(sc[3]));
  const float s2 = fmaxf((mx2 - mn2) / 255.0f, 1e-8f);
  const float r2 = 1.0f / s2;

  const int t = threadIdx.x;
  const int lane = t & 63;
  const int l15 = lane & 15;
  const int q = lane >> 4;
  const int wv = t >> 6;
  const int sp0 = blockIdx.x * 128 + wv * 32;

  int spf[2], nn[2], hwf[2], hf[2], wf[2];
#pragma unroll
  for (int f = 0; f < 2; f++) {
    spf[f] = sp0 + f * 16 + l15;
    nn[f] = spf[f] / HW;
    hwf[f] = spf[f] % HW;
    hf[f] = hwf[f] / WW;
    wf[f] = hwf[f] % WW;
  }

  f32x4 acc[2][2] = {};
  bf16x8 bz;
#pragma unroll
  for (int j = 0; j < 8; j++) bz[j] = 0;

  for (int tap = 0; tap < 9; tap++) {
    const int dh = tap / 3 - 1, dw = tap % 3 - 1;
    const u16* wA = wq2 + tap * (C3 * C2);
    const u16* bptr[2];
    bool val[2];
#pragma unroll
    for (int f = 0; f < 2; f++) {
      unsigned h2i = (unsigned)(hf[f] + dh);
      unsigned w2i = (unsigned)(wf[f] + dw);
      val[f] = (h2i < 28u) && (w2i < 28u);
      bptr[f] = h2 + ((size_t)(nn[f] * HW + (int)h2i * WW + (int)w2i)) * C2;
    }
#pragma unroll
    for (int ks = 0; ks < C2; ks += 32) {
      bf16x8 a[2], b[2];
#pragma unroll
      for (int f = 0; f < 2; f++)
        a[f] = *(const bf16x8*)(wA + (f * 16 + l15) * C2 + ks + q * 8);
#pragma unroll
      for (int f = 0; f < 2; f++) {
        if (val[f]) {
          u16x8 hv = *(const u16x8*)(bptr[f] + ks + q * 8);
          bf16x8 bb;
#pragma unroll
          for (int j = 0; j < 8; j++) {
            float h = bf2f(hv[j]);
            bb[j] = (short)f2bf(fmaf(rintf((h - mn2) * r2), s2, mn2));
          }
          b[f] = bb;
        } else {
          b[f] = bz;
        }
      }
#pragma unroll
      for (int i = 0; i < 2; i++)
#pragma unroll
        for (int j = 0; j < 2; j++)
          acc[i][j] = __builtin_amdgcn_mfma_f32_16x16x32_bf16(a[i], b[j], acc[i][j], 0, 0, 0);
    }
  }

  // store NCHW fp32; D col = lane&15 -> consecutive hw -> coalesced
#pragma unroll
  for (int i = 0; i < 2; i++) {
    int co = i * 16 + q * 4;
#pragma unroll
    for (int j = 0; j < 2; j++) {
#pragma unroll
      for (int r = 0; r < 4; r++)
        out[(nn[j] * C3 + co + r) * HW + hwf[j]] = acc[i][j][r];
    }
  }
}

// ---------------------------------------------------------------------------
extern "C" void kernel_launch(void* const* d_in, const int* in_sizes, int n_in,
                              void* d_out, int out_size, void* d_ws, size_t ws_size,
                              hipStream_t stream) {
  const float* x  = (const float*)d_in[0];
  const float* g1 = (const float*)d_in[1];
  const float* b1 = (const float*)d_in[2];
  const float* m1 = (const float*)d_in[3];
  const float* v1 = (const float*)d_in[4];
  const float* w1 = (const float*)d_in[5];
  const float* g2 = (const float*)d_in[6];
  const float* b2 = (const float*)d_in[7];
  const float* m2 = (const float*)d_in[8];
  const float* v2 = (const float*)d_in[9];
  const float* w2 = (const float*)d_in[10];
  unsigned char* ws = (unsigned char*)d_ws;
  float* out = (float*)d_out;

  kw_kernel<<<2, 256, 0, stream>>>(g1, b1, m1, v1, w1, g2, b2, m2, v2, w2, ws);
  k1_minmax<<<2048, 256, 0, stream>>>(x, ws);
  conv1_kernel<<<NHW / 128, 256, 0, stream>>>(x, ws);
  conv2_kernel<<<NHW / 128, 256, 0, stream>>>(ws, out);
}

// Round 4
// 380.688 us; speedup vs baseline: 1.5414x; 1.5414x over previous
//
#include <hip/hip_runtime.h>

typedef unsigned short u16;
typedef unsigned short u16x4 __attribute__((ext_vector_type(4)));
typedef unsigned short u16x8 __attribute__((ext_vector_type(8)));
typedef short bf16x8 __attribute__((ext_vector_type(8)));
typedef float f32x4 __attribute__((ext_vector_type(4)));

#define EPSF 1e-5f

// Geometry
#define NB   64
#define C1   512
#define C2   128
#define C3   32
#define HH   28
#define WW   28
#define HW   784            // 28*28
#define NHW  50176          // 64*784
#define XELEMS 25690112     // 64*512*784
#define K1_BLOCKS 512
#define CONV_BLOCKS 392     // NHW/128

// ws layout (bytes)
#define WS_BN1I   64        // 512 f32
#define WS_BN1B   2112      // 512 f32
#define WS_BN2I   4160      // 128 f32
#define WS_BN2B   4672      // 128 f32
#define WS_WQ1    5376      // 128*512 bf16   -> ends 136448
#define WS_WQ2    136448    // 9*32*128 bf16  -> ends 210176
#define WS_P1     210176    // 512 float2 partials (k1)   -> ends 214272
#define WS_P2     214272    // 392 float2 partials (conv1)-> ends 217408
#define WS_H2     217600    // 50176*128 bf16 (NHWC)

__device__ __forceinline__ float bf2f(u16 u) { return __uint_as_float(((unsigned)u) << 16); }
__device__ __forceinline__ u16 f2bf(float f) {
  unsigned x = __float_as_uint(f);
  return (u16)((x + 0x7fffu + ((x >> 16) & 1u)) >> 16);
}
// bit-level non-finite -> 0; no-op for clean data
__device__ __forceinline__ float finz(float f) {
  unsigned u = __float_as_uint(f);
  return ((u & 0x7f800000u) == 0x7f800000u) ? 0.0f : f;
}

// ---------------------------------------------------------------------------
// K_w: weight quantization + BN tables.  2 blocks x 256.
// ---------------------------------------------------------------------------
__global__ void kw_kernel(const float* g1, const float* be1, const float* m1, const float* v1,
                          const float* w1,
                          const float* g2, const float* be2, const float* m2, const float* v2,
                          const float* w2, unsigned char* ws) {
  float* bn1i = (float*)(ws + WS_BN1I);
  float* bn1b = (float*)(ws + WS_BN1B);
  float* bn2i = (float*)(ws + WS_BN2I);
  float* bn2b = (float*)(ws + WS_BN2B);
  u16* wq1 = (u16*)(ws + WS_WQ1);
  u16* wq2 = (u16*)(ws + WS_WQ2);
  __shared__ float red[512];
  const int t = threadIdx.x;

  if (blockIdx.x == 0) {
    for (int c = t; c < C1; c += 256) {
      float inv = g1[c] / sqrtf(v1[c] + EPSF);
      bn1i[c] = inv;
      bn1b[c] = be1[c] - m1[c] * inv;
    }
    if (t < C2) {
      float inv = g2[t] / sqrtf(v2[t] + EPSF);
      bn2i[t] = inv;
      bn2b[t] = be2[t] - m2[t] * inv;
    }
    float mn = 3.4e38f, mx = -3.4e38f;
    for (int i = t; i < C2 * C1; i += 256) {
      float f = finz(w1[i]); mn = fminf(mn, f); mx = fmaxf(mx, f);
    }
    red[t] = mn; red[256 + t] = mx;
    __syncthreads();
    for (int s = 128; s > 0; s >>= 1) {
      if (t < s) { red[t] = fminf(red[t], red[t + s]); red[256 + t] = fmaxf(red[256 + t], red[256 + t + s]); }
      __syncthreads();
    }
    mn = red[0]; mx = red[256];
    float scale = fmaxf((mx - mn) / 255.0f, 1e-8f);
    float rs = 1.0f / scale;
    for (int i = t; i < C2 * C1; i += 256) {
      float f = finz(w1[i]);
      wq1[i] = f2bf(fmaf(rintf((f - mn) * rs), scale, mn));
    }
  } else {
    float mn = 3.4e38f, mx = -3.4e38f;
    for (int i = t; i < C3 * C2 * 9; i += 256) {
      float f = finz(w2[i]); mn = fminf(mn, f); mx = fmaxf(mx, f);
    }
    red[t] = mn; red[256 + t] = mx;
    __syncthreads();
    for (int s = 128; s > 0; s >>= 1) {
      if (t < s) { red[t] = fminf(red[t], red[t + s]); red[256 + t] = fmaxf(red[256 + t], red[256 + t + s]); }
      __syncthreads();
    }
    mn = red[0]; mx = red[256];
    float scale = fmaxf((mx - mn) / 255.0f, 1e-8f);
    float rs = 1.0f / scale;
    for (int o = t; o < C3 * C2 * 9; o += 256) {
      int tap = o >> 12;            // 0..8
      int rem = o & 4095;           // co*128 + ci
      float f = finz(w2[rem * 9 + tap]);
      wq2[o] = f2bf(fmaf(rintf((f - mn) * rs), scale, mn));
    }
  }
}

// ---------------------------------------------------------------------------
// K1: min/max of relu(bn1(x)).  Per-block partial -> ws (NO atomics).
// ---------------------------------------------------------------------------
__global__ __launch_bounds__(256) void k1_minmax(const float* __restrict__ x, unsigned char* ws) {
  const float* bn1i = (const float*)(ws + WS_BN1I);
  const float* bn1b = (const float*)(ws + WS_BN1B);
  float2* p1 = (float2*)(ws + WS_P1);
  int gid = blockIdx.x * blockDim.x + threadIdx.x;
  int stride = gridDim.x * blockDim.x;
  const int ngroups = XELEMS / 4;
  float mn = 3.4e38f, mx = 0.0f;
  for (int i = gid; i < ngroups; i += stride) {
    int base = i * 4;
    int c = (base / HW) & (C1 - 1);        // 784 % 4 == 0 -> group is single-channel
    float inv = bn1i[c], bb = bn1b[c];
    f32x4 u = *((const f32x4*)x + i);
#pragma unroll
    for (int j = 0; j < 4; j++) {
      float f = finz(fmaxf(fmaf(u[j], inv, bb), 0.0f));
      mn = fminf(mn, f); mx = fmaxf(mx, f);
    }
  }
  for (int m = 32; m; m >>= 1) {
    mn = fminf(mn, __shfl_xor(mn, m));
    mx = fmaxf(mx, __shfl_xor(mx, m));
  }
  __shared__ float wmn[4], wmx[4];
  const int wv = threadIdx.x >> 6;
  if ((threadIdx.x & 63) == 0) { wmn[wv] = mn; wmx[wv] = mx; }
  __syncthreads();
  if (threadIdx.x == 0) {
    float2 pr;
    pr.x = fminf(fminf(wmn[0], wmn[1]), fminf(wmn[2], wmn[3]));
    pr.y = fmaxf(fmaxf(wmx[0], wmx[1]), fmaxf(wmx[2], wmx[3]));
    p1[blockIdx.x] = pr;
  }
}

// ---------------------------------------------------------------------------
// conv1: 1x1 conv as MFMA GEMM.  C[co=128][sp] = wq1[128x512] * xq[512][sp].
// Preamble: reduce 512 k1-partials.  Epilogue: bn2+relu -> h2 bf16 NHWC +
// per-block min/max partial to ws (NO atomics).
// ---------------------------------------------------------------------------
__global__ __launch_bounds__(256) void conv1_kernel(const float* __restrict__ x,
                                                    unsigned char* ws) {
  const float* bn1i = (const float*)(ws + WS_BN1I);
  const float* bn1b = (const float*)(ws + WS_BN1B);
  const float* bn2i = (const float*)(ws + WS_BN2I);
  const float* bn2b = (const float*)(ws + WS_BN2B);
  const u16* wq1 = (const u16*)(ws + WS_WQ1);
  const float2* p1 = (const float2*)(ws + WS_P1);
  float2* p2 = (float2*)(ws + WS_P2);
  u16* h2 = (u16*)(ws + WS_H2);

  __shared__ __align__(16) u16 Alds[128 * 40];   // [co][k], pad row to 40
  __shared__ __align__(16) u16 Blds[128 * 40];   // [sp][k] transposed, pad 40
  __shared__ float bc[2];
  __shared__ float wred[8];

  const int t = threadIdx.x;
  const int sp0 = blockIdx.x * 128;

  // ---- preamble: global min/max from 512 partials (LDS scratch = Alds/Blds)
  {
    float* rmn = (float*)Alds;
    float* rmx = (float*)Blds;
    float2 a = p1[t];
    float2 b = p1[t + 256];
    rmn[t] = fminf(a.x, b.x);
    rmx[t] = fmaxf(a.y, b.y);
    __syncthreads();
    for (int s = 128; s > 0; s >>= 1) {
      if (t < s) { rmn[t] = fminf(rmn[t], rmn[t + s]); rmx[t] = fmaxf(rmx[t], rmx[t + s]); }
      __syncthreads();
    }
    if (t == 0) { bc[0] = rmn[0]; bc[1] = rmx[0]; }
    __syncthreads();
  }
  const float mn1 = bc[0];
  const float mx1 = bc[1];
  const float s1 = fmaxf((mx1 - mn1) / 255.0f, 1e-8f);
  const float r1 = 1.0f / s1;

  // x staging assignment: thread -> k-row kk (0..31), sp groups of 8
  const int kk = t >> 3;
  const int spA = (t & 7) * 8;
  const int spB = 64 + spA;
  const int ga = sp0 + spA, gb = sp0 + spB;
  const int na = ga / HW, hwa = ga % HW;
  const int nb = gb / HW, hwb = gb % HW;
  const float* xA = x + na * (C1 * HW) + hwa;
  const float* xB = x + nb * (C1 * HW) + hwb;

  // wq1 staging: thread -> co = t>>1, k offset (t&1)*16
  const int wco = t >> 1;
  const int wko = (t & 1) * 16;

  const int lane = t & 63;
  const int l15 = lane & 15;
  const int q = lane >> 4;
  const int wv = t >> 6;
  const int wy = wv >> 1;   // co half (0/1)
  const int wx = wv & 1;    // sp half (0/1)

  f32x4 acc[4][4] = {};

  for (int k0 = 0; k0 < C1; k0 += 32) {
    __syncthreads();
    {  // stage wq1 slice [128co x 32k]
      const u16* src = wq1 + wco * C1 + k0 + wko;
      u16x8 a0 = *(const u16x8*)(src);
      u16x8 a1 = *(const u16x8*)(src + 8);
      *(u16x8*)&Alds[wco * 40 + wko] = a0;
      *(u16x8*)&Alds[wco * 40 + wko + 8] = a1;
    }
    {  // stage x slice [32k x 128sp] with bn1+relu+quant, transpose into [sp][k]
      int c = k0 + kk;
      float inv = bn1i[c], bb = bn1b[c];
      f32x4 va0 = *(const f32x4*)(xA + c * HW);
      f32x4 va1 = *(const f32x4*)(xA + c * HW + 4);
      f32x4 vb0 = *(const f32x4*)(xB + c * HW);
      f32x4 vb1 = *(const f32x4*)(xB + c * HW + 4);
#pragma unroll
      for (int j = 0; j < 4; j++) {
        float f0 = finz(fmaxf(fmaf(va0[j], inv, bb), 0.0f));
        Blds[(spA + j) * 40 + kk] = f2bf(fmaf(rintf((f0 - mn1) * r1), s1, mn1));
        float f1 = finz(fmaxf(fmaf(va1[j], inv, bb), 0.0f));
        Blds[(spA + 4 + j) * 40 + kk] = f2bf(fmaf(rintf((f1 - mn1) * r1), s1, mn1));
        float g0 = finz(fmaxf(fmaf(vb0[j], inv, bb), 0.0f));
        Blds[(spB + j) * 40 + kk] = f2bf(fmaf(rintf((g0 - mn1) * r1), s1, mn1));
        float g1v = finz(fmaxf(fmaf(vb1[j], inv, bb), 0.0f));
        Blds[(spB + 4 + j) * 40 + kk] = f2bf(fmaf(rintf((g1v - mn1) * r1), s1, mn1));
      }
    }
    __syncthreads();
    bf16x8 af[4], bfr[4];
#pragma unroll
    for (int i = 0; i < 4; i++) {
      af[i] = *(const bf16x8*)&Alds[(wy * 64 + i * 16 + l15) * 40 + q * 8];
      bfr[i] = *(const bf16x8*)&Blds[(wx * 64 + i * 16 + l15) * 40 + q * 8];
    }
#pragma unroll
    for (int i = 0; i < 4; i++)
#pragma unroll
      for (int j = 0; j < 4; j++)
        acc[i][j] = __builtin_amdgcn_mfma_f32_16x16x32_bf16(af[i], bfr[j], acc[i][j], 0, 0, 0);
  }

  // epilogue: bn2 + relu, store h2 NHWC bf16, per-block min/max partial
  float lmn = 3.4e38f, lmx = 0.0f;
#pragma unroll
  for (int i = 0; i < 4; i++) {
    int cob = wy * 64 + i * 16 + q * 4;           // D row = q*4 + reg
    f32x4 i2 = *(const f32x4*)&bn2i[cob];
    f32x4 b2 = *(const f32x4*)&bn2b[cob];
#pragma unroll
    for (int j = 0; j < 4; j++) {
      int sp = sp0 + wx * 64 + j * 16 + l15;      // D col = lane&15
      u16x4 v;
#pragma unroll
      for (int r = 0; r < 4; r++) {
        float h = finz(fmaxf(fmaf(acc[i][j][r], i2[r], b2[r]), 0.0f));
        v[r] = f2bf(h);
        lmn = fminf(lmn, h); lmx = fmaxf(lmx, h);
      }
      *(u16x4*)&h2[sp * C2 + cob] = v;
    }
  }
  for (int m = 32; m; m >>= 1) {
    lmn = fminf(lmn, __shfl_xor(lmn, m));
    lmx = fmaxf(lmx, __shfl_xor(lmx, m));
  }
  if (lane == 0) { wred[wv] = lmn; wred[4 + wv] = lmx; }
  __syncthreads();
  if (t == 0) {
    float2 pr;
    pr.x = fminf(fminf(wred[0], wred[1]), fminf(wred[2], wred[3]));
    pr.y = fmaxf(fmaxf(wred[4], wred[5]), fmaxf(wred[6], wred[7]));
    p2[blockIdx.x] = pr;
  }
}

// ---------------------------------------------------------------------------
// conv2: 3x3 conv (pad 1) as direct MFMA.  Preamble: reduce 392 conv1
// partials.  Output fp32 NCHW.
// ---------------------------------------------------------------------------
__global__ __launch_bounds__(256) void conv2_kernel(const unsigned char* ws,
                                                    float* __restrict__ out) {
  const u16* wq2 = (const u16*)(ws + WS_WQ2);
  const u16* h2 = (const u16*)(ws + WS_H2);
  const float2* p2 = (const float2*)(ws + WS_P2);

  __shared__ float rn[256], rx[256], bc2[2];
  const int t = threadIdx.x;
  {
    float m = 3.4e38f, M = 0.0f;
    if (t < 196) {
      float2 a = p2[t];
      float2 b = p2[t + 196];
      m = fminf(a.x, b.x); M = fmaxf(a.y, b.y);
    }
    rn[t] = m; rx[t] = M;
    __syncthreads();
    for (int s = 128; s > 0; s >>= 1) {
      if (t < s) { rn[t] = fminf(rn[t], rn[t + s]); rx[t] = fmaxf(rx[t], rx[t + s]); }
      __syncthreads();
    }
    if (t == 0) { bc2[0] = rn[0]; bc2[1] = rx[0]; }
    __syncthreads();
  }
  const float mn2 = bc2[0];
  const float mx2 = bc2[1];
  const float s2 = fmaxf((mx2 - mn2) / 255.0f, 1e-8f);
  const float r2 = 1.0f / s2;

  const int lane = t & 63;
  const int l15 = lane & 15;
  const int q = lane >> 4;
  const int wv = t >> 6;
  const int sp0 = blockIdx.x * 128 + wv * 32;

  int spf[2], nn[2], hwf[2], hf[2], wf[2];
#pragma unroll
  for (int f = 0; f < 2; f++) {
    spf[f] = sp0 + f * 16 + l15;
    nn[f] = spf[f] / HW;
    hwf[f] = spf[f] % HW;
    hf[f] = hwf[f] / WW;
    wf[f] = hwf[f] % WW;
  }

  f32x4 acc[2][2] = {};
  bf16x8 bz;
#pragma unroll
  for (int j = 0; j < 8; j++) bz[j] = 0;

  for (int tap = 0; tap < 9; tap++) {
    const int dh = tap / 3 - 1, dw = tap % 3 - 1;
    const u16* wA = wq2 + tap * (C3 * C2);
    const u16* bptr[2];
    bool val[2];
#pragma unroll
    for (int f = 0; f < 2; f++) {
      unsigned h2i = (unsigned)(hf[f] + dh);
      unsigned w2i = (unsigned)(wf[f] + dw);
      val[f] = (h2i < 28u) && (w2i < 28u);
      bptr[f] = h2 + ((size_t)(nn[f] * HW + (int)h2i * WW + (int)w2i)) * C2;
    }
#pragma unroll
    for (int ks = 0; ks < C2; ks += 32) {
      bf16x8 a[2], b[2];
#pragma unroll
      for (int f = 0; f < 2; f++)
        a[f] = *(const bf16x8*)(wA + (f * 16 + l15) * C2 + ks + q * 8);
#pragma unroll
      for (int f = 0; f < 2; f++) {
        if (val[f]) {
          u16x8 hv = *(const u16x8*)(bptr[f] + ks + q * 8);
          bf16x8 bb;
#pragma unroll
          for (int j = 0; j < 8; j++) {
            float h = bf2f(hv[j]);
            bb[j] = (short)f2bf(fmaf(rintf((h - mn2) * r2), s2, mn2));
          }
          b[f] = bb;
        } else {
          b[f] = bz;
        }
      }
#pragma unroll
      for (int i = 0; i < 2; i++)
#pragma unroll
        for (int j = 0; j < 2; j++)
          acc[i][j] = __builtin_amdgcn_mfma_f32_16x16x32_bf16(a[i], b[j], acc[i][j], 0, 0, 0);
    }
  }

  // store NCHW fp32; D col = lane&15 -> consecutive hw -> coalesced
#pragma unroll
  for (int i = 0; i < 2; i++) {
    int co = i * 16 + q * 4;
#pragma unroll
    for (int j = 0; j < 2; j++) {
#pragma unroll
      for (int r = 0; r < 4; r++)
        out[(nn[j] * C3 + co + r) * HW + hwf[j]] = acc[i][j][r];
    }
  }
}

// ---------------------------------------------------------------------------
extern "C" void kernel_launch(void* const* d_in, const int* in_sizes, int n_in,
                              void* d_out, int out_size, void* d_ws, size_t ws_size,
                              hipStream_t stream) {
  const float* x  = (const float*)d_in[0];
  const float* g1 = (const float*)d_in[1];
  const float* b1 = (const float*)d_in[2];
  const float* m1 = (const float*)d_in[3];
  const float* v1 = (const float*)d_in[4];
  const float* w1 = (const float*)d_in[5];
  const float* g2 = (const float*)d_in[6];
  const float* b2 = (const float*)d_in[7];
  const float* m2 = (const float*)d_in[8];
  const float* v2 = (const float*)d_in[9];
  const float* w2 = (const float*)d_in[10];
  unsigned char* ws = (unsigned char*)d_ws;
  float* out = (float*)d_out;

  kw_kernel<<<2, 256, 0, stream>>>(g1, b1, m1, v1, w1, g2, b2, m2, v2, w2, ws);
  k1_minmax<<<K1_BLOCKS, 256, 0, stream>>>(x, ws);
  conv1_kernel<<<CONV_BLOCKS, 256, 0, stream>>>(x, ws);
  conv2_kernel<<<CONV_BLOCKS, 256, 0, stream>>>(ws, out);
}

// Round 5
// 253.830 us; speedup vs baseline: 2.3118x; 1.4998x over previous
//
#include <hip/hip_runtime.h>

typedef unsigned short u16;
typedef unsigned short u16x4 __attribute__((ext_vector_type(4)));
typedef unsigned short u16x8 __attribute__((ext_vector_type(8)));
typedef short bf16x8 __attribute__((ext_vector_type(8)));
typedef float f32x4 __attribute__((ext_vector_type(4)));

#define EPSF 1e-5f

// Geometry
#define NB   64
#define C1   512
#define C2   128
#define C3   32
#define HH   28
#define WW   28
#define HW   784            // 28*28
#define NHW  50176          // 64*784
#define XELEMS 25690112     // 64*512*784
#define K1_BLOCKS 512
#define CONV_BLOCKS 392     // NHW/128
#define W1E 65536           // 128*512
#define W2E 36864           // 32*128*9

// ws layout (bytes)
#define WS_BN1I   64        // 512 f32
#define WS_BN1B   2112      // 512 f32
#define WS_BN2I   4160      // 128 f32
#define WS_BN2B   4672      // 128 f32
#define WS_WQ1    5376      // 128*512 bf16   -> ends 136448
#define WS_WQ2    136448    // 9*32*128 bf16  -> ends 210176
#define WS_P1     210176    // 512 float2 partials (k1)    -> ends 214272
#define WS_P2     214272    // 392 float2 partials (conv1) -> ends 217408
#define WS_PW1    217408    // 64 float2 partials (w1)     -> ends 217920
#define WS_PW2    217920    // 16 float2 partials (w2)     -> ends 218048
#define WS_H2     218112    // 50176*128 bf16 (NHWC)

__device__ __forceinline__ float bf2f(u16 u) { return __uint_as_float(((unsigned)u) << 16); }
__device__ __forceinline__ u16 f2bf(float f) {
  unsigned x = __float_as_uint(f);
  return (u16)((x + 0x7fffu + ((x >> 16) & 1u)) >> 16);
}
// bit-level non-finite -> 0; no-op for clean data
__device__ __forceinline__ float finz(float f) {
  unsigned u = __float_as_uint(f);
  return ((u & 0x7f800000u) == 0x7f800000u) ? 0.0f : f;
}

// block-level min/max reduce: input per-thread (mn,mx); result valid on t==0
__device__ __forceinline__ void block_minmax(float& mn, float& mx) {
  for (int m = 32; m; m >>= 1) {
    mn = fminf(mn, __shfl_xor(mn, m));
    mx = fmaxf(mx, __shfl_xor(mx, m));
  }
  __shared__ float wmn[4], wmx[4];
  const int wv = threadIdx.x >> 6;
  if ((threadIdx.x & 63) == 0) { wmn[wv] = mn; wmx[wv] = mx; }
  __syncthreads();
  if (threadIdx.x == 0) {
    mn = fminf(fminf(wmn[0], wmn[1]), fminf(wmn[2], wmn[3]));
    mx = fmaxf(fmaxf(wmx[0], wmx[1]), fmaxf(wmx[2], wmx[3]));
  }
}

// ---------------------------------------------------------------------------
// kwA: BN tables + w1/w2 min/max partials.  81 blocks x 256.
//   blocks 0..63  : w1 partial (1024 elems each, f32x4)
//   blocks 64..79 : w2 partial (2304 elems each)
//   block  80     : BN1 + BN2 tables
// ---------------------------------------------------------------------------
__global__ __launch_bounds__(256) void kwA_kernel(const float* g1, const float* be1,
                                                  const float* m1, const float* v1,
                                                  const float* w1,
                                                  const float* g2, const float* be2,
                                                  const float* m2, const float* v2,
                                                  const float* w2, unsigned char* ws) {
  const int t = threadIdx.x;
  const int b = blockIdx.x;
  float2* pw1 = (float2*)(ws + WS_PW1);
  float2* pw2 = (float2*)(ws + WS_PW2);

  if (b == 80) {
    float* bn1i = (float*)(ws + WS_BN1I);
    float* bn1b = (float*)(ws + WS_BN1B);
    float* bn2i = (float*)(ws + WS_BN2I);
    float* bn2b = (float*)(ws + WS_BN2B);
    for (int c = t; c < C1; c += 256) {
      float inv = g1[c] / sqrtf(v1[c] + EPSF);
      bn1i[c] = inv;
      bn1b[c] = be1[c] - m1[c] * inv;
    }
    if (t < C2) {
      float inv = g2[t] / sqrtf(v2[t] + EPSF);
      bn2i[t] = inv;
      bn2b[t] = be2[t] - m2[t] * inv;
    }
    return;
  }

  float mn = 3.4e38f, mx = -3.4e38f;
  if (b < 64) {
    f32x4 v = *(const f32x4*)(w1 + b * 1024 + t * 4);
#pragma unroll
    for (int j = 0; j < 4; j++) {
      float f = finz(v[j]); mn = fminf(mn, f); mx = fmaxf(mx, f);
    }
    block_minmax(mn, mx);
    if (t == 0) pw1[b] = make_float2(mn, mx);
  } else {
    const int base = (b - 64) * 2304;
#pragma unroll
    for (int j = 0; j < 9; j++) {
      float f = finz(w2[base + t + j * 256]); mn = fminf(mn, f); mx = fmaxf(mx, f);
    }
    block_minmax(mn, mx);
    if (t == 0) pw2[b - 64] = make_float2(mn, mx);
  }
}

// ---------------------------------------------------------------------------
// kwB: reduce weight partials, quantize w1 -> wq1 bf16, quantize+pack w2 ->
// wq2 bf16 [tap][co][ci].  80 blocks x 256.
// ---------------------------------------------------------------------------
__global__ __launch_bounds__(256) void kwB_kernel(const float* w1, const float* w2,
                                                  unsigned char* ws) {
  const float2* pw1 = (const float2*)(ws + WS_PW1);
  const float2* pw2 = (const float2*)(ws + WS_PW2);
  u16* wq1 = (u16*)(ws + WS_WQ1);
  u16* wq2 = (u16*)(ws + WS_WQ2);
  const int t = threadIdx.x;
  const int b = blockIdx.x;
  __shared__ float bc[2];

  if (b < 64) {
    // reduce pw1 (64 partials) in wave 0
    if (t < 64) {
      float2 p = pw1[t];
      float mn = p.x, mx = p.y;
      for (int m = 32; m; m >>= 1) {
        mn = fminf(mn, __shfl_xor(mn, m));
        mx = fmaxf(mx, __shfl_xor(mx, m));
      }
      if (t == 0) { bc[0] = mn; bc[1] = mx; }
    }
    __syncthreads();
    const float mn = bc[0];
    const float s = fmaxf((bc[1] - mn) / 255.0f, 1e-8f);
    const float rs = 1.0f / s;
    f32x4 v = *(const f32x4*)(w1 + b * 1024 + t * 4);
    u16x4 o;
#pragma unroll
    for (int j = 0; j < 4; j++)
      o[j] = f2bf(fmaf(rintf((finz(v[j]) - mn) * rs), s, mn));
    *(u16x4*)(wq1 + b * 1024 + t * 4) = o;
  } else {
    if (t < 64) {
      float2 p = (t < 16) ? pw2[t] : make_float2(3.4e38f, -3.4e38f);
      float mn = p.x, mx = p.y;
      for (int m = 32; m; m >>= 1) {
        mn = fminf(mn, __shfl_xor(mn, m));
        mx = fmaxf(mx, __shfl_xor(mx, m));
      }
      if (t == 0) { bc[0] = mn; bc[1] = mx; }
    }
    __syncthreads();
    const float mn = bc[0];
    const float s = fmaxf((bc[1] - mn) / 255.0f, 1e-8f);
    const float rs = 1.0f / s;
    const int base = (b - 64) * 2304;
#pragma unroll
    for (int j = 0; j < 9; j++) {
      int o = base + t + j * 256;       // o = tap*4096 + co*128 + ci
      int tap = o >> 12;
      int rem = o & 4095;
      float f = finz(w2[rem * 9 + tap]);
      wq2[o] = f2bf(fmaf(rintf((f - mn) * rs), s, mn));
    }
  }
}

// ---------------------------------------------------------------------------
// K1: min/max of relu(bn1(x)).  Per-block partial -> ws (NO atomics).
// ---------------------------------------------------------------------------
__global__ __launch_bounds__(256) void k1_minmax(const float* __restrict__ x, unsigned char* ws) {
  const float* bn1i = (const float*)(ws + WS_BN1I);
  const float* bn1b = (const float*)(ws + WS_BN1B);
  float2* p1 = (float2*)(ws + WS_P1);
  int gid = blockIdx.x * blockDim.x + threadIdx.x;
  int stride = gridDim.x * blockDim.x;
  const int ngroups = XELEMS / 4;
  float mn = 3.4e38f, mx = 0.0f;
  for (int i = gid; i < ngroups; i += stride) {
    int base = i * 4;
    int c = (base / HW) & (C1 - 1);        // 784 % 4 == 0 -> group is single-channel
    float inv = bn1i[c], bb = bn1b[c];
    f32x4 u = *((const f32x4*)x + i);
#pragma unroll
    for (int j = 0; j < 4; j++) {
      float f = finz(fmaxf(fmaf(u[j], inv, bb), 0.0f));
      mn = fminf(mn, f); mx = fmaxf(mx, f);
    }
  }
  block_minmax(mn, mx);
  if (threadIdx.x == 0) p1[blockIdx.x] = make_float2(mn, mx);
}

// ---------------------------------------------------------------------------
// conv1: 1x1 conv as MFMA GEMM.  C[co=128][sp] = wq1[128x512] * xq[512][sp].
// Preamble: reduce 512 k1-partials.  Epilogue: bn2+relu -> h2 bf16 NHWC +
// per-block min/max partial to ws (NO atomics).
// ---------------------------------------------------------------------------
__global__ __launch_bounds__(256) void conv1_kernel(const float* __restrict__ x,
                                                    unsigned char* ws) {
  const float* bn1i = (const float*)(ws + WS_BN1I);
  const float* bn1b = (const float*)(ws + WS_BN1B);
  const float* bn2i = (const float*)(ws + WS_BN2I);
  const float* bn2b = (const float*)(ws + WS_BN2B);
  const u16* wq1 = (const u16*)(ws + WS_WQ1);
  const float2* p1 = (const float2*)(ws + WS_P1);
  float2* p2 = (float2*)(ws + WS_P2);
  u16* h2 = (u16*)(ws + WS_H2);

  __shared__ __align__(16) u16 Alds[128 * 40];   // [co][k], pad row to 40
  __shared__ __align__(16) u16 Blds[128 * 40];   // [sp][k] transposed, pad 40
  __shared__ float bc[2];
  __shared__ float wred[8];

  const int t = threadIdx.x;
  const int sp0 = blockIdx.x * 128;

  // ---- preamble: global min/max from 512 partials (LDS scratch = Alds/Blds)
  {
    float* rmn = (float*)Alds;
    float* rmx = (float*)Blds;
    float2 a = p1[t];
    float2 b = p1[t + 256];
    rmn[t] = fminf(a.x, b.x);
    rmx[t] = fmaxf(a.y, b.y);
    __syncthreads();
    for (int s = 128; s > 0; s >>= 1) {
      if (t < s) { rmn[t] = fminf(rmn[t], rmn[t + s]); rmx[t] = fmaxf(rmx[t], rmx[t + s]); }
      __syncthreads();
    }
    if (t == 0) { bc[0] = rmn[0]; bc[1] = rmx[0]; }
    __syncthreads();
  }
  const float mn1 = bc[0];
  const float mx1 = bc[1];
  const float s1 = fmaxf((mx1 - mn1) / 255.0f, 1e-8f);
  const float r1 = 1.0f / s1;

  // x staging assignment: thread -> k-row kk (0..31), sp groups of 8
  const int kk = t >> 3;
  const int spA = (t & 7) * 8;
  const int spB = 64 + spA;
  const int ga = sp0 + spA, gb = sp0 + spB;
  const int na = ga / HW, hwa = ga % HW;
  const int nb = gb / HW, hwb = gb % HW;
  const float* xA = x + na * (C1 * HW) + hwa;
  const float* xB = x + nb * (C1 * HW) + hwb;

  // wq1 staging: thread -> co = t>>1, k offset (t&1)*16
  const int wco = t >> 1;
  const int wko = (t & 1) * 16;

  const int lane = t & 63;
  const int l15 = lane & 15;
  const int q = lane >> 4;
  const int wv = t >> 6;
  const int wy = wv >> 1;   // co half (0/1)
  const int wx = wv & 1;    // sp half (0/1)

  f32x4 acc[4][4] = {};

  for (int k0 = 0; k0 < C1; k0 += 32) {
    __syncthreads();
    {  // stage wq1 slice [128co x 32k]
      const u16* src = wq1 + wco * C1 + k0 + wko;
      u16x8 a0 = *(const u16x8*)(src);
      u16x8 a1 = *(const u16x8*)(src + 8);
      *(u16x8*)&Alds[wco * 40 + wko] = a0;
      *(u16x8*)&Alds[wco * 40 + wko + 8] = a1;
    }
    {  // stage x slice [32k x 128sp] with bn1+relu+quant, transpose into [sp][k]
      int c = k0 + kk;
      float inv = bn1i[c], bb = bn1b[c];
      f32x4 va0 = *(const f32x4*)(xA + c * HW);
      f32x4 va1 = *(const f32x4*)(xA + c * HW + 4);
      f32x4 vb0 = *(const f32x4*)(xB + c * HW);
      f32x4 vb1 = *(const f32x4*)(xB + c * HW + 4);
#pragma unroll
      for (int j = 0; j < 4; j++) {
        float f0 = finz(fmaxf(fmaf(va0[j], inv, bb), 0.0f));
        Blds[(spA + j) * 40 + kk] = f2bf(fmaf(rintf((f0 - mn1) * r1), s1, mn1));
        float f1 = finz(fmaxf(fmaf(va1[j], inv, bb), 0.0f));
        Blds[(spA + 4 + j) * 40 + kk] = f2bf(fmaf(rintf((f1 - mn1) * r1), s1, mn1));
        float g0 = finz(fmaxf(fmaf(vb0[j], inv, bb), 0.0f));
        Blds[(spB + j) * 40 + kk] = f2bf(fmaf(rintf((g0 - mn1) * r1), s1, mn1));
        float g1v = finz(fmaxf(fmaf(vb1[j], inv, bb), 0.0f));
        Blds[(spB + 4 + j) * 40 + kk] = f2bf(fmaf(rintf((g1v - mn1) * r1), s1, mn1));
      }
    }
    __syncthreads();
    bf16x8 af[4], bfr[4];
#pragma unroll
    for (int i = 0; i < 4; i++) {
      af[i] = *(const bf16x8*)&Alds[(wy * 64 + i * 16 + l15) * 40 + q * 8];
      bfr[i] = *(const bf16x8*)&Blds[(wx * 64 + i * 16 + l15) * 40 + q * 8];
    }
#pragma unroll
    for (int i = 0; i < 4; i++)
#pragma unroll
      for (int j = 0; j < 4; j++)
        acc[i][j] = __builtin_amdgcn_mfma_f32_16x16x32_bf16(af[i], bfr[j], acc[i][j], 0, 0, 0);
  }

  // epilogue: bn2 + relu, store h2 NHWC bf16, per-block min/max partial
  float lmn = 3.4e38f, lmx = 0.0f;
#pragma unroll
  for (int i = 0; i < 4; i++) {
    int cob = wy * 64 + i * 16 + q * 4;           // D row = q*4 + reg
    f32x4 i2 = *(const f32x4*)&bn2i[cob];
    f32x4 b2 = *(const f32x4*)&bn2b[cob];
#pragma unroll
    for (int j = 0; j < 4; j++) {
      int sp = sp0 + wx * 64 + j * 16 + l15;      // D col = lane&15
      u16x4 v;
#pragma unroll
      for (int r = 0; r < 4; r++) {
        float h = finz(fmaxf(fmaf(acc[i][j][r], i2[r], b2[r]), 0.0f));
        v[r] = f2bf(h);
        lmn = fminf(lmn, h); lmx = fmaxf(lmx, h);
      }
      *(u16x4*)&h2[sp * C2 + cob] = v;
    }
  }
  for (int m = 32; m; m >>= 1) {
    lmn = fminf(lmn, __shfl_xor(lmn, m));
    lmx = fmaxf(lmx, __shfl_xor(lmx, m));
  }
  if (lane == 0) { wred[wv] = lmn; wred[4 + wv] = lmx; }
  __syncthreads();
  if (t == 0) {
    float2 pr;
    pr.x = fminf(fminf(wred[0], wred[1]), fminf(wred[2], wred[3]));
    pr.y = fmaxf(fmaxf(wred[4], wred[5]), fmaxf(wred[6], wred[7]));
    p2[blockIdx.x] = pr;
  }
}

// ---------------------------------------------------------------------------
// conv2: 3x3 conv (pad 1) as direct MFMA.  Preamble: reduce 392 conv1
// partials.  Output fp32 NCHW.
// ---------------------------------------------------------------------------
__global__ __launch_bounds__(256) void conv2_kernel(const unsigned char* ws,
                                                    float* __restrict__ out) {
  const u16* wq2 = (const u16*)(ws + WS_WQ2);
  const u16* h2 = (const u16*)(ws + WS_H2);
  const float2* p2 = (const float2*)(ws + WS_P2);

  __shared__ float rn[256], rx[256], bc2[2];
  const int t = threadIdx.x;
  {
    float m = 3.4e38f, M = 0.0f;
    if (t < 196) {
      float2 a = p2[t];
      float2 b = p2[t + 196];
      m = fminf(a.x, b.x); M = fmaxf(a.y, b.y);
    }
    rn[t] = m; rx[t] = M;
    __syncthreads();
    for (int s = 128; s > 0; s >>= 1) {
      if (t < s) { rn[t] = fminf(rn[t], rn[t + s]); rx[t] = fmaxf(rx[t], rx[t + s]); }
      __syncthreads();
    }
    if (t == 0) { bc2[0] = rn[0]; bc2[1] = rx[0]; }
    __syncthreads();
  }
  const float mn2 = bc2[0];
  const float mx2 = bc2[1];
  const float s2 = fmaxf((mx2 - mn2) / 255.0f, 1e-8f);
  const float r2 = 1.0f / s2;

  const int lane = t & 63;
  const int l15 = lane & 15;
  const int q = lane >> 4;
  const int wv = t >> 6;
  const int sp0 = blockIdx.x * 128 + wv * 32;

  int spf[2], nn[2], hwf[2], hf[2], wf[2];
#pragma unroll
  for (int f = 0; f < 2; f++) {
    spf[f] = sp0 + f * 16 + l15;
    nn[f] = spf[f] / HW;
    hwf[f] = spf[f] % HW;
    hf[f] = hwf[f] / WW;
    wf[f] = hwf[f] % WW;
  }

  f32x4 acc[2][2] = {};
  bf16x8 bz;
#pragma unroll
  for (int j = 0; j < 8; j++) bz[j] = 0;

  for (int tap = 0; tap < 9; tap++) {
    const int dh = tap / 3 - 1, dw = tap % 3 - 1;
    const u16* wA = wq2 + tap * (C3 * C2);
    const u16* bptr[2];
    bool val[2];
#pragma unroll
    for (int f = 0; f < 2; f++) {
      unsigned h2i = (unsigned)(hf[f] + dh);
      unsigned w2i = (unsigned)(wf[f] + dw);
      val[f] = (h2i < 28u) && (w2i < 28u);
      bptr[f] = h2 + ((size_t)(nn[f] * HW + (int)h2i * WW + (int)w2i)) * C2;
    }
#pragma unroll
    for (int ks = 0; ks < C2; ks += 32) {
      bf16x8 a[2], b[2];
#pragma unroll
      for (int f = 0; f < 2; f++)
        a[f] = *(const bf16x8*)(wA + (f * 16 + l15) * C2 + ks + q * 8);
#pragma unroll
      for (int f = 0; f < 2; f++) {
        if (val[f]) {
          u16x8 hv = *(const u16x8*)(bptr[f] + ks + q * 8);
          bf16x8 bb;
#pragma unroll
          for (int j = 0; j < 8; j++) {
            float h = bf2f(hv[j]);
            bb[j] = (short)f2bf(fmaf(rintf((h - mn2) * r2), s2, mn2));
          }
          b[f] = bb;
        } else {
          b[f] = bz;
        }
      }
#pragma unroll
      for (int i = 0; i < 2; i++)
#pragma unroll
        for (int j = 0; j < 2; j++)
          acc[i][j] = __builtin_amdgcn_mfma_f32_16x16x32_bf16(a[i], b[j], acc[i][j], 0, 0, 0);
    }
  }

  // store NCHW fp32; D col = lane&15 -> consecutive hw -> coalesced
#pragma unroll
  for (int i = 0; i < 2; i++) {
    int co = i * 16 + q * 4;
#pragma unroll
    for (int j = 0; j < 2; j++) {
#pragma unroll
      for (int r = 0; r < 4; r++)
        out[(nn[j] * C3 + co + r) * HW + hwf[j]] = acc[i][j][r];
    }
  }
}

// ---------------------------------------------------------------------------
extern "C" void kernel_launch(void* const* d_in, const int* in_sizes, int n_in,
                              void* d_out, int out_size, void* d_ws, size_t ws_size,
                              hipStream_t stream) {
  const float* x  = (const float*)d_in[0];
  const float* g1 = (const float*)d_in[1];
  const float* b1 = (const float*)d_in[2];
  const float* m1 = (const float*)d_in[3];
  const float* v1 = (const float*)d_in[4];
  const float* w1 = (const float*)d_in[5];
  const float* g2 = (const float*)d_in[6];
  const float* b2 = (const float*)d_in[7];
  const float* m2 = (const float*)d_in[8];
  const float* v2 = (const float*)d_in[9];
  const float* w2 = (const float*)d_in[10];
  unsigned char* ws = (unsigned char*)d_ws;
  float* out = (float*)d_out;

  kwA_kernel<<<81, 256, 0, stream>>>(g1, b1, m1, v1, w1, g2, b2, m2, v2, w2, ws);
  kwB_kernel<<<80, 256, 0, stream>>>(w1, w2, ws);
  k1_minmax<<<K1_BLOCKS, 256, 0, stream>>>(x, ws);
  conv1_kernel<<<CONV_BLOCKS, 256, 0, stream>>>(x, ws);
  conv2_kernel<<<CONV_BLOCKS, 256, 0, stream>>>(ws, out);
}